// Round 8
// baseline (178.729 us; speedup 1.0000x reference)
//
#include <hip/hip_runtime.h>

// Fourier-shift patch reassembly = two circulant matmuls + rank-1 term, on MFMA.
//   U[r,x] = sum_m P~[r,m] px[x-m+96] ;  V[y,x] = sum_r U[r,x] py[y-r+96]
//   out[b,y,x] = sum_c (-1)^{x+y} ( V - sx sy Qt ) / M^2
// Split-bf16 (x = hi+lo): hi*hi + hi*lo + lo*hi ~ fp32.
// A-fragments for stage A come straight from global memory into registers
// (no sP LDS round-trip). Circulant operands read from REVERSED 8-copy
// aligned tables: R[j] = px2[223-j]; frag = b128 at copy a=(-j0)&7, slot j0+a.
// LDS: sTab 12.8KB + sU (U^T, chunk-swizzled) 32KB -> 45.6KB => 3 WGs/CU.

#define NCH 16
#define CG  2
#define WPB 8

typedef __attribute__((ext_vector_type(8))) short bf16x8;
typedef __attribute__((ext_vector_type(4))) float f32x4;
typedef __attribute__((ext_vector_type(2))) uint uint2v;

__device__ __forceinline__ ushort f2bf(float x) {
    union { float f; uint u; } v; v.f = x;
    uint r = v.u + 0x7fffu + ((v.u >> 16) & 1u);
    return (ushort)(r >> 16);
}
__device__ __forceinline__ float bf2f(ushort h) {
    union { uint u; float f; } v; v.u = ((uint)h) << 16; return v.f;
}
__device__ __forceinline__ int uSw(int x) { return (x ^ (x >> 3)) & 7; }

template<bool USE_WS>
__global__ __launch_bounds__(256, 3)
void reassemble_mfma(const float* __restrict__ patches,
                     const float* __restrict__ positions,
                     float* __restrict__ dst, int B)
{
    __shared__ __align__(16) ushort sTab[2][2][8][200]; // [x/y][hi/lo][copy][slot]
    __shared__ __align__(16) ushort sU[2][8192];        // [hi/lo] U^T swizzled
    __shared__ float sQ[4];

    const int tid  = threadIdx.x;
    const int lane = tid & 63;
    const int wv   = tid >> 6;    // wave 0..3
    const int nn   = lane & 15;   // frag row/col
    const int hh   = lane >> 4;   // frag k-group 0..3

    int b, cg;
    if (B == 128) {  // XCD-aware: all 8 WGs of an image on one XCD's L2
        const int xcd = blockIdx.x & 7, slot = blockIdx.x >> 3;
        b = xcd * 16 + (slot >> 3); cg = slot & 7;
    } else { b = blockIdx.x >> 3; cg = blockIdx.x & 7; }

    const f32x4 zero = {0.f, 0.f, 0.f, 0.f};
    f32x4 acc[2][8];                      // stage-B: ty in {2wv,2wv+1} x 8 tx
    #pragma unroll
    for (int i = 0; i < 2; ++i)
        #pragma unroll
        for (int j = 0; j < 8; ++j) acc[i][j] = zero;
    float Stot = 0.f;

    const float PI = 3.14159265358979323846f;

    for (int cc = 0; cc < CG; ++cc) {
        const int c = cg * CG + cc;
        __syncthreads();   // prev channel's stage-B readers done with sTab/sU

        const float dy = positions[(b * NCH + c) * 2 + 0];
        const float dx = positions[(b * NCH + c) * 2 + 1];
        float kdxf = rintf(dx), kdyf = rintf(dy);
        float sx = sinf((dx - kdxf) * PI); if (((int)kdxf) & 1) sx = -sx;
        float sy = sinf((dy - kdyf) * PI); if (((int)kdyf) & 1) sy = -sy;

        // ---- reversed duplicated split tables: R[j] = px2[223-j] ----
        for (int job = tid; job < 384; job += 256) {
            const int tbl = (job >= 192) ? 1 : 0;
            const int j   = job - 192 * tbl;
            const float d  = tbl ? dy : dx;
            const float sd = tbl ? sy : sx;
            const int t = 223 - j;
            float u   = (float)t - d;
            float ur  = u - 128.f * rintf(u * (1.f / 128.f));
            float th  = ur * (PI / 128.f);
            float sth = sinf(th), cth = cosf(th);
            float v = (fabsf(sth) < 1e-12f) ? ((t & 1) ? 128.f : -128.f)
                                            : sd * cth / sth;
            const ushort hi = f2bf(v);
            const ushort lo = f2bf(v - bf2f(hi));
            #pragma unroll
            for (int a = 0; a < 8; ++a) {
                sTab[tbl][0][a][j + a] = hi;
                sTab[tbl][1][a][j + a] = lo;
            }
        }

        // ---- per-lane stage-A A-fragments straight from global + Q partial ----
        bf16x8 Ah[2], Al[2];
        float qp = 0.f;
        {
            const float* src = patches + (size_t)b * 65536 + c;
            const int r = 16 * wv + nn;
            #pragma unroll
            for (int ks = 0; ks < 2; ++ks) {
                #pragma unroll
                for (int d8 = 0; d8 < 8; ++d8) {
                    const int m = 32 * ks + 8 * hh + d8;
                    const float v  = src[(size_t)(r * 64 + m) * 16];
                    const float sv = ((r + m) & 1) ? -v : v;
                    qp += sv;
                    const ushort h = f2bf(sv);
                    const ushort l = f2bf(sv - bf2f(h));
                    Ah[ks][d8] = (short)h;
                    Al[ks][d8] = (short)l;
                }
            }
        }
        #pragma unroll
        for (int off = 32; off >= 1; off >>= 1) qp += __shfl_down(qp, off, 64);
        if (lane == 0) sQ[wv] = qp;

        __syncthreads();   // tables + sQ ready

        Stot += sx * sy * (sQ[0] + sQ[1] + sQ[2] + sQ[3]);

        // ---- stage A (MFMA): U rows 16wv..16wv+15; 8 x-tiles; K=64, 3 splits ----
        f32x4 accA[8];
        #pragma unroll
        for (int tx = 0; tx < 8; ++tx) accA[tx] = zero;

        #pragma unroll
        for (int ks = 0; ks < 2; ++ks) {
            #pragma unroll
            for (int tx = 0; tx < 8; ++tx) {
                const int e0 = 16 * tx + nn + 96 - 32 * ks - 8 * hh;
                const int j0 = 223 - e0;
                const int a  = (-j0) & 7;
                const bf16x8 Bh = *(const bf16x8*)&sTab[0][0][a][j0 + a];
                const bf16x8 Bl = *(const bf16x8*)&sTab[0][1][a][j0 + a];
                accA[tx] = __builtin_amdgcn_mfma_f32_16x16x32_bf16(Ah[ks], Bh, accA[tx], 0, 0, 0);
                accA[tx] = __builtin_amdgcn_mfma_f32_16x16x32_bf16(Ah[ks], Bl, accA[tx], 0, 0, 0);
                accA[tx] = __builtin_amdgcn_mfma_f32_16x16x32_bf16(Al[ks], Bh, accA[tx], 0, 0, 0);
            }
        }

        // ---- U -> split-bf16 U^T LDS (rows r0..r0+3 packed as one b64) ----
        {
            const int r0 = 16 * wv + 4 * hh;
            #pragma unroll
            for (int tx = 0; tx < 8; ++tx) {
                const int x = 16 * tx + nn;
                ushort h[4], l[4];
                #pragma unroll
                for (int g = 0; g < 4; ++g) {
                    h[g] = f2bf(accA[tx][g]);
                    l[g] = f2bf(accA[tx][g] - bf2f(h[g]));
                }
                const int idx = x * 64 + ((((r0 >> 3) ^ uSw(x))) << 3) + (r0 & 7);
                uint2v H, L;
                H[0] = (uint)h[0] | ((uint)h[1] << 16); H[1] = (uint)h[2] | ((uint)h[3] << 16);
                L[0] = (uint)l[0] | ((uint)l[1] << 16); L[1] = (uint)l[2] | ((uint)l[3] << 16);
                *(uint2v*)&sU[0][idx] = H;
                *(uint2v*)&sU[1][idx] = L;
            }
        }

        __syncthreads();   // U^T ready

        // ---- stage B (MFMA): ty in {2wv, 2wv+1} x 8 tx; Bu read once, used 3x ----
        #pragma unroll
        for (int ks = 0; ks < 2; ++ks) {
            bf16x8 A0h, A1h, A0l, A1l;
            {
                const int e0 = 16 * (2 * wv + 0) + nn + 96 - 32 * ks - 8 * hh;
                const int j0 = 223 - e0, a = (-j0) & 7;
                A0h = *(const bf16x8*)&sTab[1][0][a][j0 + a];
                A0l = *(const bf16x8*)&sTab[1][1][a][j0 + a];
            }
            {
                const int e0 = 16 * (2 * wv + 1) + nn + 96 - 32 * ks - 8 * hh;
                const int j0 = 223 - e0, a = (-j0) & 7;
                A1h = *(const bf16x8*)&sTab[1][0][a][j0 + a];
                A1l = *(const bf16x8*)&sTab[1][1][a][j0 + a];
            }
            const int rc = 4 * ks + hh;
            #pragma unroll
            for (int tx = 0; tx < 8; ++tx) {
                const int x = 16 * tx + nn;
                const int base = x * 64 + ((rc ^ uSw(x)) << 3);
                const bf16x8 Bu0 = *(const bf16x8*)&sU[0][base];
                const bf16x8 Bu1 = *(const bf16x8*)&sU[1][base];
                acc[0][tx] = __builtin_amdgcn_mfma_f32_16x16x32_bf16(A0h, Bu0, acc[0][tx], 0, 0, 0);
                acc[1][tx] = __builtin_amdgcn_mfma_f32_16x16x32_bf16(A1h, Bu0, acc[1][tx], 0, 0, 0);
                acc[0][tx] = __builtin_amdgcn_mfma_f32_16x16x32_bf16(A0h, Bu1, acc[0][tx], 0, 0, 0);
                acc[1][tx] = __builtin_amdgcn_mfma_f32_16x16x32_bf16(A1h, Bu1, acc[1][tx], 0, 0, 0);
                acc[0][tx] = __builtin_amdgcn_mfma_f32_16x16x32_bf16(A0l, Bu0, acc[0][tx], 0, 0, 0);
                acc[1][tx] = __builtin_amdgcn_mfma_f32_16x16x32_bf16(A1l, Bu0, acc[1][tx], 0, 0, 0);
            }
        }
    }

    // ---- epilogue: sign, rank-1 correction, scale ----
    const float inv = 1.f / 16384.f;
    if (USE_WS) {
        float* pb = dst + (size_t)(b * WPB + cg) * 16384;
        #pragma unroll
        for (int tyl = 0; tyl < 2; ++tyl)
            #pragma unroll
            for (int g = 0; g < 4; ++g) {
                const int y = 16 * (2 * wv + tyl) + 4 * hh + g;
                #pragma unroll
                for (int tx = 0; tx < 8; ++tx) {
                    const int x = 16 * tx + nn;
                    const float v = (acc[tyl][tx][g] - Stot) * inv;
                    pb[y * 128 + x] = ((x + y) & 1) ? -v : v;
                }
            }
    } else {
        float* ob = dst + (size_t)b * 16384;
        #pragma unroll
        for (int tyl = 0; tyl < 2; ++tyl)
            #pragma unroll
            for (int g = 0; g < 4; ++g) {
                const int y = 16 * (2 * wv + tyl) + 4 * hh + g;
                #pragma unroll
                for (int tx = 0; tx < 8; ++tx) {
                    const int x = 16 * tx + nn;
                    const float v = (acc[tyl][tx][g] - Stot) * inv;
                    atomicAdd(&ob[y * 128 + x], ((x + y) & 1) ? -v : v);
                }
            }
    }
}

__global__ __launch_bounds__(256)
void reduce_kernel(const float* __restrict__ ws, float* __restrict__ out, int B)
{
    const int t4 = blockIdx.x * 256 + threadIdx.x;
    if (t4 >= B * 4096) return;
    const int b = t4 >> 12, q = t4 & 4095;
    const f32x4* w4 = (const f32x4*)ws;
    f32x4 s = w4[(size_t)(b * WPB) * 4096 + q];
    #pragma unroll
    for (int g = 1; g < WPB; ++g) {
        f32x4 v = w4[(size_t)(b * WPB + g) * 4096 + q];
        s[0] += v[0]; s[1] += v[1]; s[2] += v[2]; s[3] += v[3];
    }
    ((f32x4*)out)[t4] = s;
}

extern "C" void kernel_launch(void* const* d_in, const int* in_sizes, int n_in,
                              void* d_out, int out_size, void* d_ws, size_t ws_size,
                              hipStream_t stream)
{
    const float* patches   = (const float*)d_in[0];
    const float* positions = (const float*)d_in[1];
    float* out = (float*)d_out;

    const int B = in_sizes[1] / (NCH * 2);                        // 128
    const size_t need = (size_t)B * WPB * 16384 * sizeof(float);  // 67 MB

    if (ws_size >= need) {
        reassemble_mfma<true><<<dim3(B * WPB), dim3(256), 0, stream>>>(
            patches, positions, (float*)d_ws, B);
        reduce_kernel<<<dim3((B * 4096 + 255) / 256), dim3(256), 0, stream>>>(
            (const float*)d_ws, out, B);
    } else {
        hipMemsetAsync(d_out, 0, (size_t)out_size * sizeof(float), stream);
        reassemble_mfma<false><<<dim3(B * WPB), dim3(256), 0, stream>>>(
            patches, positions, out, B);
    }
}

// Round 9
// 116.307 us; speedup vs baseline: 1.5367x; 1.5367x over previous
//
#include <hip/hip_runtime.h>

// Fourier-shift patch reassembly = two circulant matmuls + rank-1 term, on MFMA.
//   U[r,x] = sum_m P~[r,m] px[x-m+96] ;  V[y,x] = sum_r U[r,x] py[y-r+96]
//   out[b,y,x] = sum_c (-1)^{x+y} ( V - sx sy Qt ) / M^2
// Split-bf16 (x = hi+lo): hi*hi + hi*lo + lo*hi ~ fp32.
// Round-4 skeleton (CG=4, WPB=4, 512 WGs, XCD-grouped). ONE change vs round-4:
// the WG's 4 channels are 16B-contiguous -> prefetch ALL patch data as f32x4
// channel-quads ONCE before the channel loop (16 loads/lane total), keep in
// registers, build per-channel A-fragments from regs. sP LDS round-trip gone.
// Channel loop unrolled so raw[][][cc] is compile-time indexed (no scratch).

#define NCH 16
#define CG  4
#define WPB 4

typedef __attribute__((ext_vector_type(8))) short bf16x8;
typedef __attribute__((ext_vector_type(4))) float f32x4;
typedef __attribute__((ext_vector_type(2))) uint uint2v;

__device__ __forceinline__ ushort f2bf(float x) {
    union { float f; uint u; } v; v.f = x;
    uint r = v.u + 0x7fffu + ((v.u >> 16) & 1u);
    return (ushort)(r >> 16);
}
__device__ __forceinline__ float bf2f(ushort h) {
    union { uint u; float f; } v; v.u = ((uint)h) << 16; return v.f;
}
__device__ __forceinline__ int uSw(int x) { return (x ^ (x >> 3)) & 7; }

template<bool USE_WS>
__global__ __launch_bounds__(256, 2)
void reassemble_mfma(const float* __restrict__ patches,
                     const float* __restrict__ positions,
                     float* __restrict__ dst, int B)
{
    __shared__ __align__(16) ushort sTab[2][2][8][200]; // [x/y][hi/lo][copy][slot]
    __shared__ __align__(16) ushort sU[2][8192];        // [hi/lo] U^T swizzled
    __shared__ float sQ[4];

    const int tid  = threadIdx.x;
    const int lane = tid & 63;
    const int wv   = tid >> 6;    // wave 0..3
    const int nn   = lane & 15;   // frag row/col
    const int hh   = lane >> 4;   // frag k-group 0..3

    int b, cg;
    if (B == 128) {  // round-4 XCD map: all 4 WGs of an image on one XCD's L2
        const int xcd = blockIdx.x & 7, slot = blockIdx.x >> 3;
        b = xcd * 16 + (slot >> 2); cg = slot & 3;
    } else { b = blockIdx.x >> 2; cg = blockIdx.x & 3; }

    const f32x4 zero = {0.f, 0.f, 0.f, 0.f};
    f32x4 acc[2][8];                      // stage-B: ty in {2wv,2wv+1} x 8 tx
    #pragma unroll
    for (int i = 0; i < 2; ++i)
        #pragma unroll
        for (int j = 0; j < 8; ++j) acc[i][j] = zero;
    float Stot = 0.f;

    const float PI = 3.14159265358979323846f;
    const int r = 16 * wv + nn;           // this lane's patch row (stage A)

    // ---- ONE-TIME prefetch: all 4 channels of this WG, 16 x f32x4 per lane ----
    // raw[ks][d8] = patches[b][r][32ks+8hh+d8][4cg .. 4cg+3]
    f32x4 raw[2][8];
    {
        const float* srcq = patches + (size_t)b * 65536 + 4 * cg;
        #pragma unroll
        for (int ks = 0; ks < 2; ++ks)
            #pragma unroll
            for (int d8 = 0; d8 < 8; ++d8) {
                const int m = 32 * ks + 8 * hh + d8;
                raw[ks][d8] = *(const f32x4*)&srcq[(size_t)(r * 64 + m) * 16];
            }
    }

    #pragma unroll
    for (int cc = 0; cc < CG; ++cc) {     // MUST be unrolled: raw[..][..][cc]
        const int c = cg * CG + cc;
        __syncthreads();   // prev channel's stage-B readers done with sTab/sU

        const float dy = positions[(b * NCH + c) * 2 + 0];
        const float dx = positions[(b * NCH + c) * 2 + 1];
        float kdxf = rintf(dx), kdyf = rintf(dy);
        float sx = sinf((dx - kdxf) * PI); if (((int)kdxf) & 1) sx = -sx;
        float sy = sinf((dy - kdyf) * PI); if (((int)kdyf) & 1) sy = -sy;

        // ---- reversed duplicated split tables: R[j] = px2[223-j] ----
        for (int job = tid; job < 384; job += 256) {
            const int tbl = (job >= 192) ? 1 : 0;
            const int j   = job - 192 * tbl;
            const float d  = tbl ? dy : dx;
            const float sd = tbl ? sy : sx;
            const int t = 223 - j;
            float u   = (float)t - d;
            float ur  = u - 128.f * rintf(u * (1.f / 128.f));
            float th  = ur * (PI / 128.f);
            float sth = sinf(th), cth = cosf(th);
            float v = (fabsf(sth) < 1e-12f) ? ((t & 1) ? 128.f : -128.f)
                                            : sd * cth / sth;
            const ushort hi = f2bf(v);
            const ushort lo = f2bf(v - bf2f(hi));
            #pragma unroll
            for (int a = 0; a < 8; ++a) {
                sTab[tbl][0][a][j + a] = hi;
                sTab[tbl][1][a][j + a] = lo;
            }
        }

        // ---- A-fragments for this channel from prefetched registers ----
        bf16x8 Ah[2], Al[2];
        float qp = 0.f;
        #pragma unroll
        for (int ks = 0; ks < 2; ++ks) {
            #pragma unroll
            for (int d8 = 0; d8 < 8; ++d8) {
                const int m = 32 * ks + 8 * hh + d8;
                const float v  = raw[ks][d8][cc];
                const float sv = ((r + m) & 1) ? -v : v;
                qp += sv;
                const ushort h = f2bf(sv);
                const ushort l = f2bf(sv - bf2f(h));
                Ah[ks][d8] = (short)h;
                Al[ks][d8] = (short)l;
            }
        }
        #pragma unroll
        for (int off = 32; off >= 1; off >>= 1) qp += __shfl_down(qp, off, 64);
        if (lane == 0) sQ[wv] = qp;

        __syncthreads();   // tables + sQ ready

        Stot += sx * sy * (sQ[0] + sQ[1] + sQ[2] + sQ[3]);

        // ---- stage A (MFMA): U rows 16wv..16wv+15; 8 x-tiles; K=64, 3 splits ----
        f32x4 accA[8];
        #pragma unroll
        for (int tx = 0; tx < 8; ++tx) accA[tx] = zero;

        #pragma unroll
        for (int ks = 0; ks < 2; ++ks) {
            #pragma unroll
            for (int tx = 0; tx < 8; ++tx) {
                const int e0 = 16 * tx + nn + 96 - 32 * ks - 8 * hh;
                const int j0 = 223 - e0;
                const int a  = (-j0) & 7;
                const bf16x8 Bh = *(const bf16x8*)&sTab[0][0][a][j0 + a];
                const bf16x8 Bl = *(const bf16x8*)&sTab[0][1][a][j0 + a];
                accA[tx] = __builtin_amdgcn_mfma_f32_16x16x32_bf16(Ah[ks], Bh, accA[tx], 0, 0, 0);
                accA[tx] = __builtin_amdgcn_mfma_f32_16x16x32_bf16(Ah[ks], Bl, accA[tx], 0, 0, 0);
                accA[tx] = __builtin_amdgcn_mfma_f32_16x16x32_bf16(Al[ks], Bh, accA[tx], 0, 0, 0);
            }
        }

        // ---- U -> split-bf16 U^T LDS (rows r0..r0+3 packed as one b64) ----
        {
            const int r0 = 16 * wv + 4 * hh;
            #pragma unroll
            for (int tx = 0; tx < 8; ++tx) {
                const int x = 16 * tx + nn;
                ushort h[4], l[4];
                #pragma unroll
                for (int g = 0; g < 4; ++g) {
                    h[g] = f2bf(accA[tx][g]);
                    l[g] = f2bf(accA[tx][g] - bf2f(h[g]));
                }
                const int idx = x * 64 + ((((r0 >> 3) ^ uSw(x))) << 3) + (r0 & 7);
                uint2v H, L;
                H[0] = (uint)h[0] | ((uint)h[1] << 16); H[1] = (uint)h[2] | ((uint)h[3] << 16);
                L[0] = (uint)l[0] | ((uint)l[1] << 16); L[1] = (uint)l[2] | ((uint)l[3] << 16);
                *(uint2v*)&sU[0][idx] = H;
                *(uint2v*)&sU[1][idx] = L;
            }
        }

        __syncthreads();   // U^T ready

        // ---- stage B (MFMA): ty in {2wv, 2wv+1} x 8 tx; Bu read once, used 3x ----
        #pragma unroll
        for (int ks = 0; ks < 2; ++ks) {
            bf16x8 A0h, A1h, A0l, A1l;
            {
                const int e0 = 16 * (2 * wv + 0) + nn + 96 - 32 * ks - 8 * hh;
                const int j0 = 223 - e0, a = (-j0) & 7;
                A0h = *(const bf16x8*)&sTab[1][0][a][j0 + a];
                A0l = *(const bf16x8*)&sTab[1][1][a][j0 + a];
            }
            {
                const int e0 = 16 * (2 * wv + 1) + nn + 96 - 32 * ks - 8 * hh;
                const int j0 = 223 - e0, a = (-j0) & 7;
                A1h = *(const bf16x8*)&sTab[1][0][a][j0 + a];
                A1l = *(const bf16x8*)&sTab[1][1][a][j0 + a];
            }
            const int rc = 4 * ks + hh;
            #pragma unroll
            for (int tx = 0; tx < 8; ++tx) {
                const int x = 16 * tx + nn;
                const int base = x * 64 + ((rc ^ uSw(x)) << 3);
                const bf16x8 Bu0 = *(const bf16x8*)&sU[0][base];
                const bf16x8 Bu1 = *(const bf16x8*)&sU[1][base];
                acc[0][tx] = __builtin_amdgcn_mfma_f32_16x16x32_bf16(A0h, Bu0, acc[0][tx], 0, 0, 0);
                acc[1][tx] = __builtin_amdgcn_mfma_f32_16x16x32_bf16(A1h, Bu0, acc[1][tx], 0, 0, 0);
                acc[0][tx] = __builtin_amdgcn_mfma_f32_16x16x32_bf16(A0h, Bu1, acc[0][tx], 0, 0, 0);
                acc[1][tx] = __builtin_amdgcn_mfma_f32_16x16x32_bf16(A1h, Bu1, acc[1][tx], 0, 0, 0);
                acc[0][tx] = __builtin_amdgcn_mfma_f32_16x16x32_bf16(A0l, Bu0, acc[0][tx], 0, 0, 0);
                acc[1][tx] = __builtin_amdgcn_mfma_f32_16x16x32_bf16(A1l, Bu0, acc[1][tx], 0, 0, 0);
            }
        }
    }

    // ---- epilogue: sign, rank-1 correction, scale ----
    const float inv = 1.f / 16384.f;
    if (USE_WS) {
        float* pb = dst + (size_t)(b * WPB + cg) * 16384;
        #pragma unroll
        for (int tyl = 0; tyl < 2; ++tyl)
            #pragma unroll
            for (int g = 0; g < 4; ++g) {
                const int y = 16 * (2 * wv + tyl) + 4 * hh + g;
                #pragma unroll
                for (int tx = 0; tx < 8; ++tx) {
                    const int x = 16 * tx + nn;
                    const float v = (acc[tyl][tx][g] - Stot) * inv;
                    pb[y * 128 + x] = ((x + y) & 1) ? -v : v;
                }
            }
    } else {
        float* ob = dst + (size_t)b * 16384;
        #pragma unroll
        for (int tyl = 0; tyl < 2; ++tyl)
            #pragma unroll
            for (int g = 0; g < 4; ++g) {
                const int y = 16 * (2 * wv + tyl) + 4 * hh + g;
                #pragma unroll
                for (int tx = 0; tx < 8; ++tx) {
                    const int x = 16 * tx + nn;
                    const float v = (acc[tyl][tx][g] - Stot) * inv;
                    atomicAdd(&ob[y * 128 + x], ((x + y) & 1) ? -v : v);
                }
            }
    }
}

__global__ __launch_bounds__(256)
void reduce_kernel(const float* __restrict__ ws, float* __restrict__ out, int B)
{
    const int t4 = blockIdx.x * 256 + threadIdx.x;
    if (t4 >= B * 4096) return;
    const int b = t4 >> 12, q = t4 & 4095;
    const f32x4* w4 = (const f32x4*)ws;
    f32x4 s = w4[(size_t)(b * WPB) * 4096 + q];
    #pragma unroll
    for (int g = 1; g < WPB; ++g) {
        f32x4 v = w4[(size_t)(b * WPB + g) * 4096 + q];
        s[0] += v[0]; s[1] += v[1]; s[2] += v[2]; s[3] += v[3];
    }
    ((f32x4*)out)[t4] = s;
}

extern "C" void kernel_launch(void* const* d_in, const int* in_sizes, int n_in,
                              void* d_out, int out_size, void* d_ws, size_t ws_size,
                              hipStream_t stream)
{
    const float* patches   = (const float*)d_in[0];
    const float* positions = (const float*)d_in[1];
    float* out = (float*)d_out;

    const int B = in_sizes[1] / (NCH * 2);                        // 128
    const size_t need = (size_t)B * WPB * 16384 * sizeof(float);  // 33.5 MB

    if (ws_size >= need) {
        reassemble_mfma<true><<<dim3(B * WPB), dim3(256), 0, stream>>>(
            patches, positions, (float*)d_ws, B);
        reduce_kernel<<<dim3((B * 4096 + 255) / 256), dim3(256), 0, stream>>>(
            (const float*)d_ws, out, B);
    } else {
        hipMemsetAsync(d_out, 0, (size_t)out_size * sizeof(float), stream);
        reassemble_mfma<false><<<dim3(B * WPB), dim3(256), 0, stream>>>(
            patches, positions, out, B);
    }
}